// Round 14
// baseline (195.245 us; speedup 1.0000x reference)
//
#include <hip/hip_runtime.h>

// LIF neuron scan over time (dim 0).
// x: (T=8, 16, 64, 56, 56) f32.  Per spatial element, sequential over t:
//   mem   = (mem_old - spike_prev) * 0.25 + x[t]
//   spike = round(clip(mem, 0, 4))      // round-half-to-even, like jnp.round
// out[t] = spike.
//
// R1/R4/R6/R12: 62-65us, ~2.45 TB/s combined, pinned across 4 structures
// (MLP attempts re-sunk by compiler; NT stores no effect on FETCH; occupancy
// 58->41% no effect). Little's law says MLP=1 should saturate -> limiter is
// memory-system-side for THIS pattern. Invariant never varied: 16 interleaved
// streams/thread with 1 KB/wave per stream visit. This round: K=4 consecutive
// chunks per thread -> 4 KB contiguous per wave per stream visit (4x fewer
// DRAM stream switches) + natural MLP=4 within each t-visit.
// R13: broker timeout, no data. Identical resubmit.

#pragma clang fp contract(off)

constexpr int   LIF_T     = 8;
constexpr float LIF_DECAY = 0.25f;
constexpr int   K         = 4;     // consecutive float4 chunks per thread

typedef float f32x4 __attribute__((ext_vector_type(4)));

__device__ __forceinline__ float lif_q4(float m)
{
    #pragma clang fp contract(off)
    return rintf(fminf(fmaxf(m, 0.f), 4.f));
}

__global__ __launch_bounds__(256) void
lif_kernel(const f32x4* __restrict__ x, f32x4* __restrict__ out, int ngroups, int n4)
{
    #pragma clang fp contract(off)

    const int g = blockIdx.x * blockDim.x + threadIdx.x;
    if (g >= ngroups) return;
    const int c0 = g * K;           // first of K consecutive chunks

    float mem[K][4];
    float spk[K][4];
    #pragma unroll
    for (int k = 0; k < K; ++k)
        #pragma unroll
        for (int c = 0; c < 4; ++c) { mem[k][c] = 0.f; spk[k][c] = 0.f; }

    #pragma unroll
    for (int t = 0; t < LIF_T; ++t) {
        // 4 independent loads, one per consecutive chunk -> wave reads
        // 4 KB contiguous from this t-slice in one burst, MLP=4.
        f32x4 v[K];
        #pragma unroll
        for (int k = 0; k < K; ++k)
            v[k] = x[t * n4 + c0 + k];

        #pragma unroll
        for (int k = 0; k < K; ++k) {
            f32x4 o;
            #pragma unroll
            for (int c = 0; c < 4; ++c) {
                mem[k][c] = (mem[k][c] - spk[k][c]) * LIF_DECAY + v[k][c];
                spk[k][c] = lif_q4(mem[k][c]);
                o[c]      = spk[k][c];
            }
            out[t * n4 + c0 + k] = o;
        }
    }
}

// Scalar fallback for elements not covered by the K-chunk kernel.
__global__ void
lif_kernel_tail(const float* __restrict__ x, float* __restrict__ out,
                int n_per_t, int start)
{
    #pragma clang fp contract(off)
    const int i = start + blockIdx.x * blockDim.x + threadIdx.x;
    if (i >= n_per_t) return;

    float mem = 0.f, spike = 0.f;
    #pragma unroll
    for (int t = 0; t < LIF_T; ++t) {
        mem   = (mem - spike) * LIF_DECAY + x[t * n_per_t + i];
        spike = rintf(fminf(fmaxf(mem, 0.f), 4.f));
        out[t * n_per_t + i] = spike;
    }
}

extern "C" void kernel_launch(void* const* d_in, const int* in_sizes, int n_in,
                              void* d_out, int out_size, void* d_ws, size_t ws_size,
                              hipStream_t stream)
{
    const float* x   = (const float*)d_in[0];
    float*       out = (float*)d_out;

    const int n_total = in_sizes[0];          // T * N
    const int n_per_t = n_total / LIF_T;      // spatial elements per timestep
    const int n4      = n_per_t / 4;          // float4 chunks per timestep
    const int ngroups = n4 / K;               // K-chunk groups (802816/4=200704)

    if (ngroups > 0) {
        const int block = 256;
        const int grid  = (ngroups + block - 1) / block;   // 784 for this shape
        lif_kernel<<<grid, block, 0, stream>>>(
            (const f32x4*)x, (f32x4*)out, ngroups, n4);
    }

    const int tail_start = ngroups * K * 4;   // first element not covered
    const int tail_n     = n_per_t - tail_start;
    if (tail_n > 0) {
        const int block = 64;
        const int grid  = (tail_n + block - 1) / block;
        lif_kernel_tail<<<grid, block, 0, stream>>>(x, out, n_per_t, tail_start);
    }
}